// Round 10
// baseline (214.081 us; speedup 1.0000x reference)
//
#include <hip/hip_runtime.h>
#include <stdint.h>

typedef __attribute__((ext_vector_type(8)))  short s16x8;   // 8 x bf16
typedef __attribute__((ext_vector_type(16))) float f32x16;  // 32x32 MFMA acc

union CvtI4 { int4 i; s16x8 s; };

__device__ __forceinline__ unsigned f2bf(float f) {
    union { float f; unsigned u; } v; v.f = f;
    return (v.u + 0x7fffu + ((v.u >> 16) & 1u)) >> 16;     // RNE
}

// ---------------------------------------------------------------------------
// k_prep: grid 1024 = (b, n0-chunk, half). LDS-transpose x tile ->
//   xT[b][n][c] = bf16(x * sqrt(log2e/8)), vbf[b][c][n] = bf16(relu(bn1(w1.x)))
// ---------------------------------------------------------------------------
__global__ __launch_bounds__(256) void k_prep(
    const float* __restrict__ x, const float* __restrict__ w1,
    const float* __restrict__ g1, const float* __restrict__ b1,
    const float* __restrict__ m1, const float* __restrict__ v1,
    unsigned short* __restrict__ xT, unsigned short* __restrict__ vbf)
{
    __shared__ float X[64 * 65];   // [c][n] pad+1
    const int b    = blockIdx.x >> 7;
    const int n0   = ((blockIdx.x >> 1) & 63) << 6;
    const int half = blockIdx.x & 1;
    const int tid  = threadIdx.x;
    const float QS = 0.42466090014400953f;   // sqrt(log2(e)/8)

    {
        const int r = tid >> 6, nn = tid & 63;
        const float* xb = x + (size_t)b * 262144 + n0 + nn;
#pragma unroll
        for (int cc = 0; cc < 16; ++cc) {
            int c = cc * 4 + r;
            X[c * 65 + nn] = xb[(size_t)c * 4096];
        }
    }
    __syncthreads();

    {   // xT: 32 n rows, 8 threads per 128B row
        const int n8 = tid >> 3, c8 = tid & 7;
        const int n = (half << 5) + n8;
        unsigned u[4];
#pragma unroll
        for (int j = 0; j < 4; ++j) {
            unsigned lo = f2bf(X[(c8 * 8 + 2 * j) * 65 + n] * QS);
            unsigned hi = f2bf(X[(c8 * 8 + 2 * j + 1) * 65 + n] * QS);
            u[j] = lo | (hi << 16);
        }
        uint4 pk; pk.x = u[0]; pk.y = u[1]; pk.z = u[2]; pk.w = u[3];
        *(uint4*)(xT + (((size_t)((b << 12) + n0 + n)) << 6) + (c8 << 3)) = pk;
    }

    {   // V = relu(bn1(conv1x1)): 32 output channels for this half
        const int n = tid & 63, og = tid >> 6;
        float rX[64];
#pragma unroll
        for (int c = 0; c < 64; ++c) rX[c] = X[c * 65 + n];
        unsigned short* vb = vbf + (((size_t)(b << 6)) << 12) + n0 + n;
#pragma unroll 2
        for (int oo = 0; oo < 8; ++oo) {
            int o = (half << 5) + og * 8 + oo;
            float inv = g1[o] * rsqrtf(v1[o] + 1e-5f);
            float sh  = b1[o] - m1[o] * inv;
            float acc = 0.f;
#pragma unroll
            for (int c = 0; c < 64; ++c) acc = fmaf(w1[o * 64 + c], rX[c], acc);
            vb[(size_t)o << 12] = (unsigned short)f2bf(fmaxf(fmaf(acc, inv, sh), 0.f));
        }
    }
}

// ---------------------------------------------------------------------------
// k_attn v10: v9 dataflow, V fragments DIRECT FROM GLOBAL (no V LDS staging).
// LDS pipe was the measured ceiling (~89% busy incl. conflicts at R9);
// removing V staging (2 ds_write + 4 ds_read b128 per wave-tile) drops it
// to ~60%. Bv rows are contiguous 16B segments of vbf (same pattern proven
// correct in R5); loads issued at loop-top, consumed after P -> latency
// hidden by QK+exp2 under the same barriers. K staging + register prefetch
// and the P LDS round-trip are unchanged from R9.
// ---------------------------------------------------------------------------
__global__ __launch_bounds__(256) void k_attn(
    const unsigned short* __restrict__ xT, const unsigned short* __restrict__ vbf,
    unsigned short* __restrict__ outO, float* __restrict__ outL,
    int tilesPer, int nsplit)
{
    __shared__ __align__(16) unsigned short Klds[64 * 64];   // [m][c] swz8
    __shared__ __align__(16) unsigned short Plds[64 * 64];   // [n][m] swz8
    __shared__ float rsLds[4][32];
    __shared__ float denomT[64];

    const int xcd  = blockIdx.x & 7;
    const int slot = blockIdx.x >> 3;
    const int qgrp = slot & 63;
    const int pair = xcd * nsplit + (slot >> 6);
    const int b = pair & 7;
    const int ms = pair >> 3;

    const int tid = threadIdx.x;
    const int w = tid >> 6, lane = tid & 63;
    const int l31 = lane & 31, half = lane >> 5;
    const int qbase = qgrp << 6;

    outO += (size_t)ms * 2097152u;   // 8*4096*64 bf16 per split
    outL += (size_t)ms * 32768u;

    const int s = w & 1;      // QK m-strip / PV d-half
    const int t = w >> 1;     // QK n-half  / PV n-half

    // Q B-fragments (held): B[k = kk*16 + 8h + j][n = (t<<5) + l31]
    s16x8 Bq[4];
    {
        const unsigned short* qr = xT +
            (((size_t)((b << 12) + qbase + (t << 5) + l31)) << 6) + (half << 3);
#pragma unroll
        for (int kk = 0; kk < 4; ++kk) {
            CvtI4 c; c.i = *(const int4*)(qr + (kk << 4));
            Bq[kk] = c.s;
        }
    }

    f32x16 O = {0.f,0.f,0.f,0.f,0.f,0.f,0.f,0.f,0.f,0.f,0.f,0.f,0.f,0.f,0.f,0.f};
    float rs = 0.f;
    const int mt0 = ms * tilesPer;

    // K staging lane mapping (tile-invariant)
    const int km0 = tid >> 3, c4 = tid & 7;          // row / 16B-chunk
    const int km1 = km0 + 32;
    const size_t kOff0 = (((size_t)((b << 12) + km0)) << 6) + (c4 << 3);
    const size_t kOff1 = (((size_t)((b << 12) + km1)) << 6) + (c4 << 3);
    unsigned short* kDst0 = Klds + (km0 << 6) + ((c4 ^ (km0 & 7)) << 3);
    unsigned short* kDst1 = Klds + (km1 << 6) + ((c4 ^ (km1 & 7)) << 3);

    // V fragment base: row d = (s<<5)+l31 of vbf, chunk parity = half
    const int drow = (s << 5) + l31;
    const unsigned short* vBase = vbf + (((size_t)((b << 6) + drow)) << 12) + (half << 3);

    // prologue: prefetch first K tile into registers
    int4 kpre0, kpre1;
    {
        const size_t m0c = (size_t)(mt0 << 6) << 6;
        kpre0 = *(const int4*)(xT + kOff0 + m0c);
        kpre1 = *(const int4*)(xT + kOff1 + m0c);
    }

    for (int mt = 0; mt < tilesPer; ++mt) {
        const int m0 = (mt0 + mt) << 6;

        // issue V fragment loads early (global, L1/L2-hot, barrier-independent)
        int4 bv0 = *(const int4*)(vBase + m0);
        int4 bv1 = *(const int4*)(vBase + m0 + 16);
        int4 bv2 = *(const int4*)(vBase + m0 + 32);
        int4 bv3 = *(const int4*)(vBase + m0 + 48);

        __syncthreads();   // prev tile's LDS reads done before restage
        *(int4*)kDst0 = kpre0;
        *(int4*)kDst1 = kpre1;
        if (mt + 1 < tilesPer) {   // issue next K tile's loads
            const size_t m1c = (size_t)((mt0 + mt + 1) << 6) << 6;
            kpre0 = *(const int4*)(xT + kOff0 + m1c);
            kpre1 = *(const int4*)(xT + kOff1 + m1c);
        }
        __syncthreads();

        {   // QK quadrant: A = K rows m = s*32 + l31, B = Bq (n-half t)
            const int km = (s << 5) + l31;
            s16x8 Ak[4];
#pragma unroll
            for (int kk = 0; kk < 4; ++kk) {
                int pos = ((kk << 1) + half) ^ (km & 7);
                Ak[kk] = *(const s16x8*)(Klds + (km << 6) + (pos << 3));
            }
            f32x16 S = {0.f,0.f,0.f,0.f,0.f,0.f,0.f,0.f,0.f,0.f,0.f,0.f,0.f,0.f,0.f,0.f};
            S = __builtin_amdgcn_mfma_f32_32x32x16_bf16(Ak[0], Bq[0], S, 0, 0, 0);
            S = __builtin_amdgcn_mfma_f32_32x32x16_bf16(Ak[1], Bq[1], S, 0, 0, 0);
            S = __builtin_amdgcn_mfma_f32_32x32x16_bf16(Ak[2], Bq[2], S, 0, 0, 0);
            S = __builtin_amdgcn_mfma_f32_32x32x16_bf16(Ak[3], Bq[3], S, 0, 0, 0);

            // P = exp2(S) -> Plds rows n = t*32 + l31, m = 32s + 8q + 4h + 0..3
            const int nrow = (t << 5) + l31;
#pragma unroll
            for (int q = 0; q < 4; ++q) {
                float p0 = __builtin_amdgcn_exp2f(S[4*q+0]);
                float p1 = __builtin_amdgcn_exp2f(S[4*q+1]);
                float p2 = __builtin_amdgcn_exp2f(S[4*q+2]);
                float p3 = __builtin_amdgcn_exp2f(S[4*q+3]);
                rs += (p0 + p1) + (p2 + p3);
                union { float f; unsigned u; } a0, a1, a2, a3;
                a0.f = p0; a1.f = p1; a2.f = p2; a3.f = p3;
                uint2 pk;   // v_perm-based bf16x2 pack (round half-up)
                pk.x = __builtin_amdgcn_perm(a1.u + 0x8000u, a0.u + 0x8000u, 0x07060302u);
                pk.y = __builtin_amdgcn_perm(a3.u + 0x8000u, a2.u + 0x8000u, 0x07060302u);
                int c8 = (s << 2) + q;             // m-chunk = (32s + 8q)/8
                *(uint2*)(Plds + (nrow << 6) + ((c8 ^ (nrow & 7)) << 3) + (half << 2)) = pk;
            }
        }
        __syncthreads();

        // PV: wave owns O quadrant (n-half = t, d-half = s), full 64 m.
        // B fragments = bv0..bv3 (global), A = P rows from LDS.
        {
            const int nrow = (t << 5) + l31;
            CvtI4 cb;
#pragma unroll
            for (int ks = 0; ks < 4; ++ks) {
                int c = (ks << 1) + half;
                const s16x8 Ap = *(const s16x8*)(Plds + (nrow << 6) + ((c ^ (nrow & 7)) << 3));
                cb.i = (ks == 0) ? bv0 : (ks == 1) ? bv1 : (ks == 2) ? bv2 : bv3;
                O = __builtin_amdgcn_mfma_f32_32x32x16_bf16(Ap, cb.s, O, 0, 0, 0);
            }
        }
    }

    // denominators: fold halves, then cross-strip (waves 2t and 2t+1) via LDS
    rs += __shfl_xor(rs, 32);
    if (half == 0) rsLds[w][l31] = rs;
    __syncthreads();
    if (tid < 64) {
        int tt = tid >> 5, n = tid & 31;
        denomT[tid] = rsLds[2 * tt][n] + rsLds[2 * tt + 1][n];
    }
    __syncthreads();

    const int nb = (b << 12) + qbase;
    const int n32o = w >> 1, d32 = w & 1;
    if (nsplit == 1) {
#pragma unroll
        for (int r = 0; r < 16; ++r) {
            int nl = (r & 3) + ((r >> 2) << 3) + (half << 2);
            int n = (n32o << 5) + nl;
            float inv = 1.f / denomT[n];
            outO[((size_t)(nb + n) << 6) + (d32 << 5) + l31] = (unsigned short)f2bf(O[r] * inv);
        }
    } else {
#pragma unroll
        for (int r = 0; r < 16; ++r) {
            int nl = (r & 3) + ((r >> 2) << 3) + (half << 2);
            int n = (n32o << 5) + nl;
            outO[((size_t)(nb + n) << 6) + (d32 << 5) + l31] = (unsigned short)f2bf(O[r]);
        }
        if (tid < 64) outL[nb + tid] = denomT[tid];
    }
}

// ---------------------------------------------------------------------------
// k_post: stage 3-row window (combining nsplit bf16 partials) into LDS ->
// dwconv3x3 + BN2 + ReLU -> LDS -> pointwise(w3) + BN3 + residual.
// grid 512 = (b, h), 256 thr.
// ---------------------------------------------------------------------------
__global__ __launch_bounds__(256) void k_post(
    const unsigned short* __restrict__ Obase, const float* __restrict__ Lbase,
    const float* __restrict__ x,
    const float* __restrict__ w2,
    const float* __restrict__ g2, const float* __restrict__ b2,
    const float* __restrict__ m2, const float* __restrict__ v2,
    const float* __restrict__ w3,
    const float* __restrict__ g3, const float* __restrict__ b3,
    const float* __restrict__ m3, const float* __restrict__ v3,
    float* __restrict__ out, int nsplit, int normalized)
{
    __shared__ float W[3][64 * 66];
    __shared__ float T2[64 * 66];

    const int b = blockIdx.x >> 6;
    const int h = blockIdx.x & 63;
    const int tid = threadIdx.x;

    // stage + combine bf16 partials: lane = (w, 8-channel chunk)
#pragma unroll
    for (int r = 0; r < 3; ++r) {
        int hh = h + r - 1;
        if (hh >= 0 && hh <= 63) {
#pragma unroll
            for (int i = 0; i < 2; ++i) {
                int lin = (i << 8) + tid;            // 512 = 64 w x 8 chunks
                int w = lin >> 3, cg = lin & 7;
                size_t npos = (size_t)((b << 12) + (hh << 6) + w);
                float acc[8];
#pragma unroll
                for (int j = 0; j < 8; ++j) acc[j] = 0.f;
                float sl = normalized ? 0.f : Lbase[npos];
                const unsigned short* p0 = Obase + (npos << 6) + (cg << 3);
                for (int s = 0; s < nsplit; ++s) {
                    uint4 v = *(const uint4*)(p0 + (size_t)s * 2097152u);
                    union { float f; unsigned u; } t;
                    t.u = v.x << 16;        acc[0] += t.f;
                    t.u = v.x & 0xFFFF0000u; acc[1] += t.f;
                    t.u = v.y << 16;        acc[2] += t.f;
                    t.u = v.y & 0xFFFF0000u; acc[3] += t.f;
                    t.u = v.z << 16;        acc[4] += t.f;
                    t.u = v.z & 0xFFFF0000u; acc[5] += t.f;
                    t.u = v.w << 16;        acc[6] += t.f;
                    t.u = v.w & 0xFFFF0000u; acc[7] += t.f;
                    if (s && !normalized) sl += Lbase[npos + (size_t)s * 32768u];
                }
                float invd = normalized ? 1.f : 1.f / sl;
                float* Wd = &W[r][w * 66 + (cg << 3)];
#pragma unroll
                for (int j = 0; j < 8; ++j) Wd[j] = acc[j] * invd;
            }
        } else {
#pragma unroll
            for (int i = 0; i < 2; ++i) {
                int lin = (i << 8) + tid;
                float* Wd = &W[r][(lin >> 3) * 66 + ((lin & 7) << 3)];
#pragma unroll
                for (int j = 0; j < 8; ++j) Wd[j] = 0.f;
            }
        }
    }
    __syncthreads();

    const int w = tid & 63, cq = tid >> 6;
    float t16[16];
#pragma unroll
    for (int i = 0; i < 16; ++i) t16[i] = 0.f;

#pragma unroll
    for (int ky = 0; ky < 3; ++ky) {
#pragma unroll
        for (int kx = 0; kx < 3; ++kx) {
            int ww = w + kx - 1;
            if (ww < 0 || ww > 63) continue;
            const int k = ky * 3 + kx;
            const float* Wr = &W[ky][ww * 66 + (cq << 4)];
#pragma unroll
            for (int i = 0; i < 4; ++i) {
                float4 a = *(const float4*)(Wr + (i << 2));
                int c = (cq << 4) + (i << 2);
                t16[i * 4 + 0] = fmaf(w2[(c + 0) * 9 + k], a.x, t16[i * 4 + 0]);
                t16[i * 4 + 1] = fmaf(w2[(c + 1) * 9 + k], a.y, t16[i * 4 + 1]);
                t16[i * 4 + 2] = fmaf(w2[(c + 2) * 9 + k], a.z, t16[i * 4 + 2]);
                t16[i * 4 + 3] = fmaf(w2[(c + 3) * 9 + k], a.w, t16[i * 4 + 3]);
            }
        }
    }
#pragma unroll
    for (int i = 0; i < 16; ++i) {
        int c = (cq << 4) + i;
        float inv = g2[c] * rsqrtf(v2[c] + 1e-5f);
        float sh  = b2[c] - m2[c] * inv;
        T2[w * 66 + c] = fmaxf(fmaf(t16[i], inv, sh), 0.f);
    }
    __syncthreads();

    float rT[64];
#pragma unroll
    for (int c4 = 0; c4 < 16; ++c4)
        *(float4*)&rT[c4 << 2] = *(const float4*)&T2[w * 66 + (c4 << 2)];

    const int hw = (h << 6) + w;
#pragma unroll 2
    for (int oo = 0; oo < 16; ++oo) {
        int o = (cq << 4) + oo;
        float inv = g3[o] * rsqrtf(v3[o] + 1e-5f);
        float sh  = b3[o] - m3[o] * inv;
        float acc = 0.f;
#pragma unroll
        for (int c = 0; c < 64; ++c) acc = fmaf(w3[o * 64 + c], rT[c], acc);
        size_t idx = (((size_t)((b << 6) + o)) << 12) + hw;
        out[idx] = fmaf(acc, inv, sh) + x[idx];
    }
}

// ---------------------------------------------------------------------------
extern "C" void kernel_launch(void* const* d_in, const int* in_sizes, int n_in,
                              void* d_out, int out_size, void* d_ws, size_t ws_size,
                              hipStream_t stream)
{
    const float* x  = (const float*)d_in[0];
    const float* w1 = (const float*)d_in[1];
    const float* g1 = (const float*)d_in[2];
    const float* b1 = (const float*)d_in[3];
    const float* m1 = (const float*)d_in[4];
    const float* v1 = (const float*)d_in[5];
    const float* w2 = (const float*)d_in[6];
    const float* g2 = (const float*)d_in[7];
    const float* b2 = (const float*)d_in[8];
    const float* m2 = (const float*)d_in[9];
    const float* v2 = (const float*)d_in[10];
    const float* w3 = (const float*)d_in[11];
    const float* g3 = (const float*)d_in[12];
    const float* b3 = (const float*)d_in[13];
    const float* m3 = (const float*)d_in[14];
    const float* v3 = (const float*)d_in[15];
    float* out = (float*)d_out;

    // ws: xT 4MB | vbf 4MB | O_s nsplit*4MB (bf16) | L_s nsplit*128KB
    unsigned short* xT  = (unsigned short*)d_ws;
    unsigned short* vbf = xT + (size_t)8 * 4096 * 64;
    unsigned short* Obase = (unsigned short*)((char*)d_ws + (8u << 20));

    const size_t need2 = (8u << 20) + 2u * ((4u << 20) + (128u << 10));
    const int nsplit = (ws_size >= need2) ? 2 : 1;
    float* Lbase = (float*)(Obase + (size_t)nsplit * 2097152u);

    k_prep<<<1024, 256, 0, stream>>>(x, w1, g1, b1, m1, v1, xT, vbf);
    k_attn<<<nsplit * 512, 256, 0, stream>>>(xT, vbf, Obase, Lbase,
                                             64 / nsplit, nsplit);
    k_post<<<512, 256, 0, stream>>>(Obase, Lbase, x, w2, g2, b2, m2, v2,
                                    w3, g3, b3, m3, v3, out, nsplit, nsplit == 1);
}

// Round 11
// 202.865 us; speedup vs baseline: 1.0553x; 1.0553x over previous
//
#include <hip/hip_runtime.h>
#include <stdint.h>

typedef __attribute__((ext_vector_type(8)))  short s16x8;   // 8 x bf16
typedef __attribute__((ext_vector_type(16))) float f32x16;  // 32x32 MFMA acc

union CvtI4 { int4 i; s16x8 s; };

__device__ __forceinline__ unsigned f2bf(float f) {
    union { float f; unsigned u; } v; v.f = f;
    return (v.u + 0x7fffu + ((v.u >> 16) & 1u)) >> 16;     // RNE
}

// ---------------------------------------------------------------------------
// k_prep: grid 1024 = (b, n0-chunk, half). LDS-transpose x tile ->
//   xT[b][n][c] = bf16(x * sqrt(log2e/8)), vbf[b][c][n] = bf16(relu(bn1(w1.x)))
// ---------------------------------------------------------------------------
__global__ __launch_bounds__(256) void k_prep(
    const float* __restrict__ x, const float* __restrict__ w1,
    const float* __restrict__ g1, const float* __restrict__ b1,
    const float* __restrict__ m1, const float* __restrict__ v1,
    unsigned short* __restrict__ xT, unsigned short* __restrict__ vbf)
{
    __shared__ float X[64 * 65];   // [c][n] pad+1
    const int b    = blockIdx.x >> 7;
    const int n0   = ((blockIdx.x >> 1) & 63) << 6;
    const int half = blockIdx.x & 1;
    const int tid  = threadIdx.x;
    const float QS = 0.42466090014400953f;   // sqrt(log2(e)/8)

    {
        const int r = tid >> 6, nn = tid & 63;
        const float* xb = x + (size_t)b * 262144 + n0 + nn;
#pragma unroll
        for (int cc = 0; cc < 16; ++cc) {
            int c = cc * 4 + r;
            X[c * 65 + nn] = xb[(size_t)c * 4096];
        }
    }
    __syncthreads();

    {   // xT: 32 n rows, 8 threads per 128B row
        const int n8 = tid >> 3, c8 = tid & 7;
        const int n = (half << 5) + n8;
        unsigned u[4];
#pragma unroll
        for (int j = 0; j < 4; ++j) {
            unsigned lo = f2bf(X[(c8 * 8 + 2 * j) * 65 + n] * QS);
            unsigned hi = f2bf(X[(c8 * 8 + 2 * j + 1) * 65 + n] * QS);
            u[j] = lo | (hi << 16);
        }
        uint4 pk; pk.x = u[0]; pk.y = u[1]; pk.z = u[2]; pk.w = u[3];
        *(uint4*)(xT + (((size_t)((b << 12) + n0 + n)) << 6) + (c8 << 3)) = pk;
    }

    {   // V = relu(bn1(conv1x1)): 32 output channels for this half
        const int n = tid & 63, og = tid >> 6;
        float rX[64];
#pragma unroll
        for (int c = 0; c < 64; ++c) rX[c] = X[c * 65 + n];
        unsigned short* vb = vbf + (((size_t)(b << 6)) << 12) + n0 + n;
#pragma unroll 2
        for (int oo = 0; oo < 8; ++oo) {
            int o = (half << 5) + og * 8 + oo;
            float inv = g1[o] * rsqrtf(v1[o] + 1e-5f);
            float sh  = b1[o] - m1[o] * inv;
            float acc = 0.f;
#pragma unroll
            for (int c = 0; c < 64; ++c) acc = fmaf(w1[o * 64 + c], rX[c], acc);
            vb[(size_t)o << 12] = (unsigned short)f2bf(fmaxf(fmaf(acc, inv, sh), 0.f));
        }
    }
}

// ---------------------------------------------------------------------------
// k_attn v11: R9 dataflow with Plds ALIASED onto Klds (K is dead after the
// Ak register loads; an extra barrier makes the overwrite safe).
// LDS 25.6 -> 17.4 KB => 9 blocks/CU fit; nsplit=4 grid 2048 = 8 blocks/CU,
// zero tail, 8 waves/SIMD (2x R9's latency hiding). 4 barriers/tile but only
// 16 tiles/wave -> fewer total barrier crossings than R9 (64 vs 96).
// ---------------------------------------------------------------------------
__global__ __launch_bounds__(256) void k_attn(
    const unsigned short* __restrict__ xT, const unsigned short* __restrict__ vbf,
    unsigned short* __restrict__ outO, float* __restrict__ outL,
    int tilesPer, int nsplit)
{
    __shared__ __align__(16) unsigned short KPlds[64 * 64];  // K, then P (aliased)
    __shared__ __align__(16) unsigned short Vlds[64 * 64];   // [d][m] swz8
    __shared__ float rsLds[4][32];
    __shared__ float denomT[64];

    const int xcd  = blockIdx.x & 7;
    const int slot = blockIdx.x >> 3;
    const int qgrp = slot & 63;
    const int pair = xcd * nsplit + (slot >> 6);
    const int b = pair & 7;
    const int ms = pair >> 3;

    const int tid = threadIdx.x;
    const int w = tid >> 6, lane = tid & 63;
    const int l31 = lane & 31, half = lane >> 5;
    const int qbase = qgrp << 6;

    outO += (size_t)ms * 2097152u;   // 8*4096*64 bf16 per split
    outL += (size_t)ms * 32768u;

    const int s = w & 1;      // QK m-strip / PV d-half
    const int t = w >> 1;     // QK n-half  / PV n-half

    // Q B-fragments (held): B[k = kk*16 + 8h + j][n = (t<<5) + l31]
    s16x8 Bq[4];
    {
        const unsigned short* qr = xT +
            (((size_t)((b << 12) + qbase + (t << 5) + l31)) << 6) + (half << 3);
#pragma unroll
        for (int kk = 0; kk < 4; ++kk) {
            CvtI4 c; c.i = *(const int4*)(qr + (kk << 4));
            Bq[kk] = c.s;
        }
    }

    f32x16 O = {0.f,0.f,0.f,0.f,0.f,0.f,0.f,0.f,0.f,0.f,0.f,0.f,0.f,0.f,0.f,0.f};
    float rs = 0.f;
    const int mt0 = ms * tilesPer;

    // staging lane mapping (tile-invariant)
    const int km0 = tid >> 3, c4 = tid & 7;          // row / 16B-chunk
    const int km1 = km0 + 32;
    const size_t kOff0 = (((size_t)((b << 12) + km0)) << 6) + (c4 << 3);
    const size_t kOff1 = (((size_t)((b << 12) + km1)) << 6) + (c4 << 3);
    const size_t vOff0 = (((size_t)((b << 6) + km0)) << 12) + (c4 << 3);
    const size_t vOff1 = (((size_t)((b << 6) + km1)) << 12) + (c4 << 3);
    unsigned short* kDst0 = KPlds + (km0 << 6) + ((c4 ^ (km0 & 7)) << 3);
    unsigned short* kDst1 = KPlds + (km1 << 6) + ((c4 ^ (km1 & 7)) << 3);
    unsigned short* vDst0 = Vlds + (km0 << 6) + ((c4 ^ (km0 & 7)) << 3);
    unsigned short* vDst1 = Vlds + (km1 << 6) + ((c4 ^ (km1 & 7)) << 3);

    // prologue: prefetch first tile into registers
    int4 kpre0, kpre1, vpre0, vpre1;
    {
        const size_t m0c = (size_t)(mt0 << 6) << 6;
        const int m0 = mt0 << 6;
        kpre0 = *(const int4*)(xT + kOff0 + m0c);
        kpre1 = *(const int4*)(xT + kOff1 + m0c);
        vpre0 = *(const int4*)(vbf + vOff0 + m0);
        vpre1 = *(const int4*)(vbf + vOff1 + m0);
    }

    for (int mt = 0; mt < tilesPer; ++mt) {
        __syncthreads();   // [A] prev tile's PV reads (P in KPlds, V) done
        *(int4*)kDst0 = kpre0;
        *(int4*)kDst1 = kpre1;
        *(int4*)vDst0 = vpre0;
        *(int4*)vDst1 = vpre1;
        if (mt + 1 < tilesPer) {   // issue next tile's loads (consumed next iter)
            const int m1 = (mt0 + mt + 1) << 6;
            const size_t m1c = (size_t)m1 << 6;
            kpre0 = *(const int4*)(xT + kOff0 + m1c);
            kpre1 = *(const int4*)(xT + kOff1 + m1c);
            vpre0 = *(const int4*)(vbf + vOff0 + m1);
            vpre1 = *(const int4*)(vbf + vOff1 + m1);
        }
        __syncthreads();   // [B] staging visible

        // Ak register loads (K rows m = s*32 + l31) — K dead after this
        const int km = (s << 5) + l31;
        s16x8 Ak[4];
#pragma unroll
        for (int kk = 0; kk < 4; ++kk) {
            int pos = ((kk << 1) + half) ^ (km & 7);
            Ak[kk] = *(const s16x8*)(KPlds + (km << 6) + (pos << 3));
        }
        __syncthreads();   // [C] all K reads done -> safe to overwrite with P

        {   // QK quadrant + P = exp2(S) -> KPlds (P layout, rows n)
            f32x16 S = {0.f,0.f,0.f,0.f,0.f,0.f,0.f,0.f,0.f,0.f,0.f,0.f,0.f,0.f,0.f,0.f};
            S = __builtin_amdgcn_mfma_f32_32x32x16_bf16(Ak[0], Bq[0], S, 0, 0, 0);
            S = __builtin_amdgcn_mfma_f32_32x32x16_bf16(Ak[1], Bq[1], S, 0, 0, 0);
            S = __builtin_amdgcn_mfma_f32_32x32x16_bf16(Ak[2], Bq[2], S, 0, 0, 0);
            S = __builtin_amdgcn_mfma_f32_32x32x16_bf16(Ak[3], Bq[3], S, 0, 0, 0);

            const int nrow = (t << 5) + l31;
#pragma unroll
            for (int q = 0; q < 4; ++q) {
                float p0 = __builtin_amdgcn_exp2f(S[4*q+0]);
                float p1 = __builtin_amdgcn_exp2f(S[4*q+1]);
                float p2 = __builtin_amdgcn_exp2f(S[4*q+2]);
                float p3 = __builtin_amdgcn_exp2f(S[4*q+3]);
                rs += (p0 + p1) + (p2 + p3);
                union { float f; unsigned u; } a0, a1, a2, a3;
                a0.f = p0; a1.f = p1; a2.f = p2; a3.f = p3;
                uint2 pk;   // v_perm bf16x2 pack (round half-up)
                pk.x = __builtin_amdgcn_perm(a1.u + 0x8000u, a0.u + 0x8000u, 0x07060302u);
                pk.y = __builtin_amdgcn_perm(a3.u + 0x8000u, a2.u + 0x8000u, 0x07060302u);
                int c8 = (s << 2) + q;             // m-chunk = (32s + 8q)/8
                *(uint2*)(KPlds + (nrow << 6) + ((c8 ^ (nrow & 7)) << 3) + (half << 2)) = pk;
            }
        }
        __syncthreads();   // [D] P visible

        // PV: wave owns O quadrant (n-half = t, d-half = s), full 64 m
        {
            const int nrow = (t << 5) + l31;          // A = P rows (n)
            const int drow = (s << 5) + l31;          // B = V rows (d)
#pragma unroll
            for (int ks = 0; ks < 4; ++ks) {
                int c = (ks << 1) + half;
                const s16x8 Ap = *(const s16x8*)(KPlds + (nrow << 6) + ((c ^ (nrow & 7)) << 3));
                const s16x8 Bv = *(const s16x8*)(Vlds + (drow << 6) + ((c ^ (drow & 7)) << 3));
                O = __builtin_amdgcn_mfma_f32_32x32x16_bf16(Ap, Bv, O, 0, 0, 0);
            }
        }
    }

    // denominators: fold halves, then cross-strip (waves 2t and 2t+1) via LDS
    rs += __shfl_xor(rs, 32);
    if (half == 0) rsLds[w][l31] = rs;
    __syncthreads();
    if (tid < 64) {
        int tt = tid >> 5, n = tid & 31;
        denomT[tid] = rsLds[2 * tt][n] + rsLds[2 * tt + 1][n];
    }
    __syncthreads();

    const int nb = (b << 12) + qbase;
    const int n32o = w >> 1, d32 = w & 1;
    if (nsplit == 1) {
#pragma unroll
        for (int r = 0; r < 16; ++r) {
            int nl = (r & 3) + ((r >> 2) << 3) + (half << 2);
            int n = (n32o << 5) + nl;
            float inv = 1.f / denomT[n];
            outO[((size_t)(nb + n) << 6) + (d32 << 5) + l31] = (unsigned short)f2bf(O[r] * inv);
        }
    } else {
#pragma unroll
        for (int r = 0; r < 16; ++r) {
            int nl = (r & 3) + ((r >> 2) << 3) + (half << 2);
            int n = (n32o << 5) + nl;
            outO[((size_t)(nb + n) << 6) + (d32 << 5) + l31] = (unsigned short)f2bf(O[r]);
        }
        if (tid < 64) outL[nb + tid] = denomT[tid];
    }
}

// ---------------------------------------------------------------------------
// k_post: stage 3-row window (combining nsplit bf16 partials) into LDS ->
// dwconv3x3 + BN2 + ReLU -> LDS -> pointwise(w3) + BN3 + residual.
// grid 512 = (b, h), 256 thr.
// ---------------------------------------------------------------------------
__global__ __launch_bounds__(256) void k_post(
    const unsigned short* __restrict__ Obase, const float* __restrict__ Lbase,
    const float* __restrict__ x,
    const float* __restrict__ w2,
    const float* __restrict__ g2, const float* __restrict__ b2,
    const float* __restrict__ m2, const float* __restrict__ v2,
    const float* __restrict__ w3,
    const float* __restrict__ g3, const float* __restrict__ b3,
    const float* __restrict__ m3, const float* __restrict__ v3,
    float* __restrict__ out, int nsplit, int normalized)
{
    __shared__ float W[3][64 * 66];
    __shared__ float T2[64 * 66];

    const int b = blockIdx.x >> 6;
    const int h = blockIdx.x & 63;
    const int tid = threadIdx.x;

    // stage + combine bf16 partials: lane = (w, 8-channel chunk)
#pragma unroll
    for (int r = 0; r < 3; ++r) {
        int hh = h + r - 1;
        if (hh >= 0 && hh <= 63) {
#pragma unroll
            for (int i = 0; i < 2; ++i) {
                int lin = (i << 8) + tid;            // 512 = 64 w x 8 chunks
                int w = lin >> 3, cg = lin & 7;
                size_t npos = (size_t)((b << 12) + (hh << 6) + w);
                float acc[8];
#pragma unroll
                for (int j = 0; j < 8; ++j) acc[j] = 0.f;
                float sl = normalized ? 0.f : Lbase[npos];
                const unsigned short* p0 = Obase + (npos << 6) + (cg << 3);
                for (int s = 0; s < nsplit; ++s) {
                    uint4 v = *(const uint4*)(p0 + (size_t)s * 2097152u);
                    union { float f; unsigned u; } t;
                    t.u = v.x << 16;        acc[0] += t.f;
                    t.u = v.x & 0xFFFF0000u; acc[1] += t.f;
                    t.u = v.y << 16;        acc[2] += t.f;
                    t.u = v.y & 0xFFFF0000u; acc[3] += t.f;
                    t.u = v.z << 16;        acc[4] += t.f;
                    t.u = v.z & 0xFFFF0000u; acc[5] += t.f;
                    t.u = v.w << 16;        acc[6] += t.f;
                    t.u = v.w & 0xFFFF0000u; acc[7] += t.f;
                    if (s && !normalized) sl += Lbase[npos + (size_t)s * 32768u];
                }
                float invd = normalized ? 1.f : 1.f / sl;
                float* Wd = &W[r][w * 66 + (cg << 3)];
#pragma unroll
                for (int j = 0; j < 8; ++j) Wd[j] = acc[j] * invd;
            }
        } else {
#pragma unroll
            for (int i = 0; i < 2; ++i) {
                int lin = (i << 8) + tid;
                float* Wd = &W[r][(lin >> 3) * 66 + ((lin & 7) << 3)];
#pragma unroll
                for (int j = 0; j < 8; ++j) Wd[j] = 0.f;
            }
        }
    }
    __syncthreads();

    const int w = tid & 63, cq = tid >> 6;
    float t16[16];
#pragma unroll
    for (int i = 0; i < 16; ++i) t16[i] = 0.f;

#pragma unroll
    for (int ky = 0; ky < 3; ++ky) {
#pragma unroll
        for (int kx = 0; kx < 3; ++kx) {
            int ww = w + kx - 1;
            if (ww < 0 || ww > 63) continue;
            const int k = ky * 3 + kx;
            const float* Wr = &W[ky][ww * 66 + (cq << 4)];
#pragma unroll
            for (int i = 0; i < 4; ++i) {
                float4 a = *(const float4*)(Wr + (i << 2));
                int c = (cq << 4) + (i << 2);
                t16[i * 4 + 0] = fmaf(w2[(c + 0) * 9 + k], a.x, t16[i * 4 + 0]);
                t16[i * 4 + 1] = fmaf(w2[(c + 1) * 9 + k], a.y, t16[i * 4 + 1]);
                t16[i * 4 + 2] = fmaf(w2[(c + 2) * 9 + k], a.z, t16[i * 4 + 2]);
                t16[i * 4 + 3] = fmaf(w2[(c + 3) * 9 + k], a.w, t16[i * 4 + 3]);
            }
        }
    }
#pragma unroll
    for (int i = 0; i < 16; ++i) {
        int c = (cq << 4) + i;
        float inv = g2[c] * rsqrtf(v2[c] + 1e-5f);
        float sh  = b2[c] - m2[c] * inv;
        T2[w * 66 + c] = fmaxf(fmaf(t16[i], inv, sh), 0.f);
    }
    __syncthreads();

    float rT[64];
#pragma unroll
    for (int c4 = 0; c4 < 16; ++c4)
        *(float4*)&rT[c4 << 2] = *(const float4*)&T2[w * 66 + (c4 << 2)];

    const int hw = (h << 6) + w;
#pragma unroll 2
    for (int oo = 0; oo < 16; ++oo) {
        int o = (cq << 4) + oo;
        float inv = g3[o] * rsqrtf(v3[o] + 1e-5f);
        float sh  = b3[o] - m3[o] * inv;
        float acc = 0.f;
#pragma unroll
        for (int c = 0; c < 64; ++c) acc = fmaf(w3[o * 64 + c], rT[c], acc);
        size_t idx = (((size_t)((b << 6) + o)) << 12) + hw;
        out[idx] = fmaf(acc, inv, sh) + x[idx];
    }
}

// ---------------------------------------------------------------------------
extern "C" void kernel_launch(void* const* d_in, const int* in_sizes, int n_in,
                              void* d_out, int out_size, void* d_ws, size_t ws_size,
                              hipStream_t stream)
{
    const float* x  = (const float*)d_in[0];
    const float* w1 = (const float*)d_in[1];
    const float* g1 = (const float*)d_in[2];
    const float* b1 = (const float*)d_in[3];
    const float* m1 = (const float*)d_in[4];
    const float* v1 = (const float*)d_in[5];
    const float* w2 = (const float*)d_in[6];
    const float* g2 = (const float*)d_in[7];
    const float* b2 = (const float*)d_in[8];
    const float* m2 = (const float*)d_in[9];
    const float* v2 = (const float*)d_in[10];
    const float* w3 = (const float*)d_in[11];
    const float* g3 = (const float*)d_in[12];
    const float* b3 = (const float*)d_in[13];
    const float* m3 = (const float*)d_in[14];
    const float* v3 = (const float*)d_in[15];
    float* out = (float*)d_out;

    // ws: xT 4MB | vbf 4MB | O_s nsplit*4MB (bf16) | L_s nsplit*128KB
    unsigned short* xT  = (unsigned short*)d_ws;
    unsigned short* vbf = xT + (size_t)8 * 4096 * 64;
    unsigned short* Obase = (unsigned short*)((char*)d_ws + (8u << 20));

    const size_t need4 = (8u << 20) + 4u * ((4u << 20) + (128u << 10));
    const size_t need2 = (8u << 20) + 2u * ((4u << 20) + (128u << 10));
    const int nsplit = (ws_size >= need4) ? 4 : (ws_size >= need2 ? 2 : 1);
    float* Lbase = (float*)(Obase + (size_t)nsplit * 2097152u);

    k_prep<<<1024, 256, 0, stream>>>(x, w1, g1, b1, m1, v1, xT, vbf);
    k_attn<<<nsplit * 512, 256, 0, stream>>>(xT, vbf, Obase, Lbase,
                                             64 / nsplit, nsplit);
    k_post<<<512, 256, 0, stream>>>(Obase, Lbase, x, w2, g2, b2, m2, v2,
                                    w3, g3, b3, m3, v3, out, nsplit, nsplit == 1);
}

// Round 12
// 192.621 us; speedup vs baseline: 1.1114x; 1.0532x over previous
//
#include <hip/hip_runtime.h>
#include <stdint.h>

typedef __attribute__((ext_vector_type(8)))  short s16x8;   // 8 x bf16
typedef __attribute__((ext_vector_type(16))) float f32x16;  // 32x32 MFMA acc

union CvtI4 { int4 i; s16x8 s; };

__device__ __forceinline__ unsigned f2bf(float f) {
    union { float f; unsigned u; } v; v.f = f;
    return (v.u + 0x7fffu + ((v.u >> 16) & 1u)) >> 16;     // RNE
}

// ---------------------------------------------------------------------------
// k_prep: grid 1024 = (b, n0-chunk, half). LDS-transpose x tile ->
//   xT[b][n][c] = bf16(x * sqrt(log2e/8)), vbf[b][c][n] = bf16(relu(bn1(w1.x)))
// ---------------------------------------------------------------------------
__global__ __launch_bounds__(256) void k_prep(
    const float* __restrict__ x, const float* __restrict__ w1,
    const float* __restrict__ g1, const float* __restrict__ b1,
    const float* __restrict__ m1, const float* __restrict__ v1,
    unsigned short* __restrict__ xT, unsigned short* __restrict__ vbf)
{
    __shared__ float X[64 * 65];   // [c][n] pad+1
    const int b    = blockIdx.x >> 7;
    const int n0   = ((blockIdx.x >> 1) & 63) << 6;
    const int half = blockIdx.x & 1;
    const int tid  = threadIdx.x;
    const float QS = 0.42466090014400953f;   // sqrt(log2(e)/8)

    {
        const int r = tid >> 6, nn = tid & 63;
        const float* xb = x + (size_t)b * 262144 + n0 + nn;
#pragma unroll
        for (int cc = 0; cc < 16; ++cc) {
            int c = cc * 4 + r;
            X[c * 65 + nn] = xb[(size_t)c * 4096];
        }
    }
    __syncthreads();

    {   // xT: 32 n rows, 8 threads per 128B row
        const int n8 = tid >> 3, c8 = tid & 7;
        const int n = (half << 5) + n8;
        unsigned u[4];
#pragma unroll
        for (int j = 0; j < 4; ++j) {
            unsigned lo = f2bf(X[(c8 * 8 + 2 * j) * 65 + n] * QS);
            unsigned hi = f2bf(X[(c8 * 8 + 2 * j + 1) * 65 + n] * QS);
            u[j] = lo | (hi << 16);
        }
        uint4 pk; pk.x = u[0]; pk.y = u[1]; pk.z = u[2]; pk.w = u[3];
        *(uint4*)(xT + (((size_t)((b << 12) + n0 + n)) << 6) + (c8 << 3)) = pk;
    }

    {   // V = relu(bn1(conv1x1)): 32 output channels for this half
        const int n = tid & 63, og = tid >> 6;
        float rX[64];
#pragma unroll
        for (int c = 0; c < 64; ++c) rX[c] = X[c * 65 + n];
        unsigned short* vb = vbf + (((size_t)(b << 6)) << 12) + n0 + n;
#pragma unroll 2
        for (int oo = 0; oo < 8; ++oo) {
            int o = (half << 5) + og * 8 + oo;
            float inv = g1[o] * rsqrtf(v1[o] + 1e-5f);
            float sh  = b1[o] - m1[o] * inv;
            float acc = 0.f;
#pragma unroll
            for (int c = 0; c < 64; ++c) acc = fmaf(w1[o * 64 + c], rX[c], acc);
            vb[(size_t)o << 12] = (unsigned short)f2bf(fmaxf(fmaf(acc, inv, sh), 0.f));
        }
    }
}

// ---------------------------------------------------------------------------
// k_attn v12: producer-consumer wave specialization.
// Block = 8 waves (512 thr): waves 0-3 = QK+softmax producers (quadrant
// (s=w&1, t=w>>1), same as R11), waves 4-7 = PV consumers (same O-quadrant
// map). K/V/P all double-buffered -> ONE barrier per tile; QK computes
// P[i+1] while PV consumes P[i]. Producers stage K (2-tiles-ahead register
// prefetch), consumers stage V. Swizzles/layouts byte-identical to R11.
// grid 512 = (b=XCD, qgrp), 2 blocks/CU, zero tail. Normalizes in-kernel.
// ---------------------------------------------------------------------------
__global__ __launch_bounds__(512) void k_attn(
    const unsigned short* __restrict__ xT, const unsigned short* __restrict__ vbf,
    unsigned short* __restrict__ outO)
{
    __shared__ __align__(16) unsigned short Klds[2][64 * 64];  // [m][c] swz8
    __shared__ __align__(16) unsigned short Vlds[2][64 * 64];  // [d][m] swz8
    __shared__ __align__(16) unsigned short Plds[2][64 * 64];  // [n][m] swz8
    __shared__ float rsLds[4][32];
    __shared__ float denomT[64];

    const int b    = blockIdx.x & 7;          // batch == XCD slice
    const int qgrp = blockIdx.x >> 3;         // 0..63
    const int tid  = threadIdx.x;
    const int w = tid >> 6, lane = tid & 63;
    const int l31 = lane & 31, half = lane >> 5;
    const int qbase = qgrp << 6;
    const int T = 64;

    const bool isQK = (w < 4);
    const int wr = isQK ? w : (w - 4);
    const int s = wr & 1;      // m-strip (QK) / d-half (PV)
    const int t = wr >> 1;     // n-half

    // ---- producer state ----
    s16x8 Bq[4];
    float rs = 0.f;
    // K staging mapping (QK lanes: tid in [0,256))
    const int kr0 = (tid & 255) >> 3, c4 = tid & 7;
    const int kr1 = kr0 + 32;
    const size_t kOff0 = (((size_t)((b << 12) + kr0)) << 6) + (c4 << 3);
    const size_t kOff1 = (((size_t)((b << 12) + kr1)) << 6) + (c4 << 3);
    const int kx0 = (c4 ^ (kr0 & 7)) << 3, kx1 = (c4 ^ (kr1 & 7)) << 3;
    // V staging mapping (PV lanes)
    const size_t vOff0 = (((size_t)((b << 6) + kr0)) << 12) + (c4 << 3);
    const size_t vOff1 = (((size_t)((b << 6) + kr1)) << 12) + (c4 << 3);

    int4 kpre0, kpre1, vpre0, vpre1;

    // ---- consumer state ----
    f32x16 O = {0.f,0.f,0.f,0.f,0.f,0.f,0.f,0.f,0.f,0.f,0.f,0.f,0.f,0.f,0.f,0.f};

    // ================= prologue =================
    if (isQK) {
        const unsigned short* qr = xT +
            (((size_t)((b << 12) + qbase + (t << 5) + l31)) << 6) + (half << 3);
#pragma unroll
        for (int kk = 0; kk < 4; ++kk) {
            CvtI4 c; c.i = *(const int4*)(qr + (kk << 4));
            Bq[kk] = c.s;
        }
        // stage K[0], K[1]; prefetch K[2]
        {
            int4 a0 = *(const int4*)(xT + kOff0);
            int4 a1 = *(const int4*)(xT + kOff1);
            *(int4*)(Klds[0] + (kr0 << 6) + kx0) = a0;
            *(int4*)(Klds[0] + (kr1 << 6) + kx1) = a1;
            a0 = *(const int4*)(xT + kOff0 + ((size_t)1 << 12));
            a1 = *(const int4*)(xT + kOff1 + ((size_t)1 << 12));
            *(int4*)(Klds[1] + (kr0 << 6) + kx0) = a0;
            *(int4*)(Klds[1] + (kr1 << 6) + kx1) = a1;
            kpre0 = *(const int4*)(xT + kOff0 + ((size_t)2 << 12));
            kpre1 = *(const int4*)(xT + kOff1 + ((size_t)2 << 12));
        }
    } else {
        // stage V[0]; prefetch V[1]
        int4 a0 = *(const int4*)(vbf + vOff0);
        int4 a1 = *(const int4*)(vbf + vOff1);
        *(int4*)(Vlds[0] + (kr0 << 6) + kx0) = a0;
        *(int4*)(Vlds[0] + (kr1 << 6) + kx1) = a1;
        vpre0 = *(const int4*)(vbf + vOff0 + (1 << 6));
        vpre1 = *(const int4*)(vbf + vOff1 + (1 << 6));
    }
    __syncthreads();

    // producers compute P[0] -> Plds[0]
    if (isQK) {
        const int km = (s << 5) + l31;
        s16x8 Ak[4];
#pragma unroll
        for (int kk = 0; kk < 4; ++kk)
            Ak[kk] = *(const s16x8*)(Klds[0] + (km << 6) + ((((kk << 1) + half) ^ (km & 7)) << 3));
        f32x16 S = {0.f,0.f,0.f,0.f,0.f,0.f,0.f,0.f,0.f,0.f,0.f,0.f,0.f,0.f,0.f,0.f};
        S = __builtin_amdgcn_mfma_f32_32x32x16_bf16(Ak[0], Bq[0], S, 0, 0, 0);
        S = __builtin_amdgcn_mfma_f32_32x32x16_bf16(Ak[1], Bq[1], S, 0, 0, 0);
        S = __builtin_amdgcn_mfma_f32_32x32x16_bf16(Ak[2], Bq[2], S, 0, 0, 0);
        S = __builtin_amdgcn_mfma_f32_32x32x16_bf16(Ak[3], Bq[3], S, 0, 0, 0);
        const int nrow = (t << 5) + l31;
#pragma unroll
        for (int q = 0; q < 4; ++q) {
            float p0 = __builtin_amdgcn_exp2f(S[4*q+0]);
            float p1 = __builtin_amdgcn_exp2f(S[4*q+1]);
            float p2 = __builtin_amdgcn_exp2f(S[4*q+2]);
            float p3 = __builtin_amdgcn_exp2f(S[4*q+3]);
            rs += (p0 + p1) + (p2 + p3);
            union { float f; unsigned u; } a0, a1, a2, a3;
            a0.f = p0; a1.f = p1; a2.f = p2; a3.f = p3;
            uint2 pk;
            pk.x = __builtin_amdgcn_perm(a1.u + 0x8000u, a0.u + 0x8000u, 0x07060302u);
            pk.y = __builtin_amdgcn_perm(a3.u + 0x8000u, a2.u + 0x8000u, 0x07060302u);
            int c8 = (s << 2) + q;
            *(uint2*)(Plds[0] + (nrow << 6) + ((c8 ^ (nrow & 7)) << 3) + (half << 2)) = pk;
        }
    }
    __syncthreads();

    // ================= main pipeline =================
    // entry invariant (phase i): Kl[(i+1)&1]=K[i+1], Pl[i&1]=P[i], Vl[i&1]=V[i],
    //                            kpre=K[i+2]c, vpre=V[i+1]
    for (int i = 0; i < T; ++i) {
        if (isQK) {
            // stage K[i+2] (clamped dup at tail, never read)
            *(int4*)(Klds[i & 1] + (kr0 << 6) + kx0) = kpre0;
            *(int4*)(Klds[i & 1] + (kr1 << 6) + kx1) = kpre1;
            {   // prefetch K[i+3]
                size_t tk = (size_t)((i + 3 < T) ? (i + 3) : (T - 1)) << 12;
                kpre0 = *(const int4*)(xT + kOff0 + tk);
                kpre1 = *(const int4*)(xT + kOff1 + tk);
            }
            if (i + 1 < T) {   // compute P[i+1] from Kl[(i+1)&1]
                const int km = (s << 5) + l31;
                const unsigned short* Kb = Klds[(i + 1) & 1];
                s16x8 Ak[4];
#pragma unroll
                for (int kk = 0; kk < 4; ++kk)
                    Ak[kk] = *(const s16x8*)(Kb + (km << 6) + ((((kk << 1) + half) ^ (km & 7)) << 3));
                f32x16 S = {0.f,0.f,0.f,0.f,0.f,0.f,0.f,0.f,0.f,0.f,0.f,0.f,0.f,0.f,0.f,0.f};
                S = __builtin_amdgcn_mfma_f32_32x32x16_bf16(Ak[0], Bq[0], S, 0, 0, 0);
                S = __builtin_amdgcn_mfma_f32_32x32x16_bf16(Ak[1], Bq[1], S, 0, 0, 0);
                S = __builtin_amdgcn_mfma_f32_32x32x16_bf16(Ak[2], Bq[2], S, 0, 0, 0);
                S = __builtin_amdgcn_mfma_f32_32x32x16_bf16(Ak[3], Bq[3], S, 0, 0, 0);
                const int nrow = (t << 5) + l31;
                unsigned short* Pb = Plds[(i + 1) & 1];
#pragma unroll
                for (int q = 0; q < 4; ++q) {
                    float p0 = __builtin_amdgcn_exp2f(S[4*q+0]);
                    float p1 = __builtin_amdgcn_exp2f(S[4*q+1]);
                    float p2 = __builtin_amdgcn_exp2f(S[4*q+2]);
                    float p3 = __builtin_amdgcn_exp2f(S[4*q+3]);
                    rs += (p0 + p1) + (p2 + p3);
                    union { float f; unsigned u; } a0, a1, a2, a3;
                    a0.f = p0; a1.f = p1; a2.f = p2; a3.f = p3;
                    uint2 pk;
                    pk.x = __builtin_amdgcn_perm(a1.u + 0x8000u, a0.u + 0x8000u, 0x07060302u);
                    pk.y = __builtin_amdgcn_perm(a3.u + 0x8000u, a2.u + 0x8000u, 0x07060302u);
                    int c8 = (s << 2) + q;
                    *(uint2*)(Pb + (nrow << 6) + ((c8 ^ (nrow & 7)) << 3) + (half << 2)) = pk;
                }
            }
        } else {
            // stage V[i+1] (clamped dup at tail, never read)
            *(int4*)(Vlds[(i + 1) & 1] + (kr0 << 6) + kx0) = vpre0;
            *(int4*)(Vlds[(i + 1) & 1] + (kr1 << 6) + kx1) = vpre1;
            {   // prefetch V[i+2]
                int tv = ((i + 2 < T) ? (i + 2) : (T - 1)) << 6;
                vpre0 = *(const int4*)(vbf + vOff0 + tv);
                vpre1 = *(const int4*)(vbf + vOff1 + tv);
            }
            // PV on tile i: A = P rows (Pl[i&1]), B = V rows (Vl[i&1])
            const int nrow = (t << 5) + l31;
            const int drow = (s << 5) + l31;
            const unsigned short* Pb = Plds[i & 1];
            const unsigned short* Vb = Vlds[i & 1];
#pragma unroll
            for (int ks = 0; ks < 4; ++ks) {
                int c = (ks << 1) + half;
                const s16x8 Ap = *(const s16x8*)(Pb + (nrow << 6) + ((c ^ (nrow & 7)) << 3));
                const s16x8 Bv = *(const s16x8*)(Vb + (drow << 6) + ((c ^ (drow & 7)) << 3));
                O = __builtin_amdgcn_mfma_f32_32x32x16_bf16(Ap, Bv, O, 0, 0, 0);
            }
        }
        __syncthreads();
    }

    // ================= epilogue =================
    if (isQK) {
        rs += __shfl_xor(rs, 32);
        if (half == 0) rsLds[w][l31] = rs;
    }
    __syncthreads();
    if (tid < 64) {
        int tt = tid >> 5, n = tid & 31;
        denomT[tid] = rsLds[2 * tt][n] + rsLds[2 * tt + 1][n];
    }
    __syncthreads();

    if (!isQK) {
        const int nb = (b << 12) + qbase;
#pragma unroll
        for (int r = 0; r < 16; ++r) {
            int nl = (r & 3) + ((r >> 2) << 3) + (half << 2);
            int n = (t << 5) + nl;
            float inv = 1.f / denomT[n];
            outO[((size_t)(nb + n) << 6) + (s << 5) + l31] = (unsigned short)f2bf(O[r] * inv);
        }
    }
}

// ---------------------------------------------------------------------------
// k_post: stage 3-row attn window (bf16, already normalized) into LDS ->
// dwconv3x3 + BN2 + ReLU -> LDS -> pointwise(w3) + BN3 + residual.
// grid 512 = (b, h), 256 thr.
// ---------------------------------------------------------------------------
__global__ __launch_bounds__(256) void k_post(
    const unsigned short* __restrict__ Obase,
    const float* __restrict__ x,
    const float* __restrict__ w2,
    const float* __restrict__ g2, const float* __restrict__ b2,
    const float* __restrict__ m2, const float* __restrict__ v2,
    const float* __restrict__ w3,
    const float* __restrict__ g3, const float* __restrict__ b3,
    const float* __restrict__ m3, const float* __restrict__ v3,
    float* __restrict__ out)
{
    __shared__ float W[3][64 * 66];
    __shared__ float T2[64 * 66];

    const int b = blockIdx.x >> 6;
    const int h = blockIdx.x & 63;
    const int tid = threadIdx.x;

#pragma unroll
    for (int r = 0; r < 3; ++r) {
        int hh = h + r - 1;
        if (hh >= 0 && hh <= 63) {
#pragma unroll
            for (int i = 0; i < 2; ++i) {
                int lin = (i << 8) + tid;            // 512 = 64 w x 8 chunks
                int w = lin >> 3, cg = lin & 7;
                size_t npos = (size_t)((b << 12) + (hh << 6) + w);
                uint4 v = *(const uint4*)(Obase + (npos << 6) + (cg << 3));
                float* Wd = &W[r][w * 66 + (cg << 3)];
                union { float f; unsigned u; } t;
                t.u = v.x << 16;         Wd[0] = t.f;
                t.u = v.x & 0xFFFF0000u; Wd[1] = t.f;
                t.u = v.y << 16;         Wd[2] = t.f;
                t.u = v.y & 0xFFFF0000u; Wd[3] = t.f;
                t.u = v.z << 16;         Wd[4] = t.f;
                t.u = v.z & 0xFFFF0000u; Wd[5] = t.f;
                t.u = v.w << 16;         Wd[6] = t.f;
                t.u = v.w & 0xFFFF0000u; Wd[7] = t.f;
            }
        } else {
#pragma unroll
            for (int i = 0; i < 2; ++i) {
                int lin = (i << 8) + tid;
                float* Wd = &W[r][(lin >> 3) * 66 + ((lin & 7) << 3)];
#pragma unroll
                for (int j = 0; j < 8; ++j) Wd[j] = 0.f;
            }
        }
    }
    __syncthreads();

    const int w = tid & 63, cq = tid >> 6;
    float t16[16];
#pragma unroll
    for (int i = 0; i < 16; ++i) t16[i] = 0.f;

#pragma unroll
    for (int ky = 0; ky < 3; ++ky) {
#pragma unroll
        for (int kx = 0; kx < 3; ++kx) {
            int ww = w + kx - 1;
            if (ww < 0 || ww > 63) continue;
            const int k = ky * 3 + kx;
            const float* Wr = &W[ky][ww * 66 + (cq << 4)];
#pragma unroll
            for (int i = 0; i < 4; ++i) {
                float4 a = *(const float4*)(Wr + (i << 2));
                int c = (cq << 4) + (i << 2);
                t16[i * 4 + 0] = fmaf(w2[(c + 0) * 9 + k], a.x, t16[i * 4 + 0]);
                t16[i * 4 + 1] = fmaf(w2[(c + 1) * 9 + k], a.y, t16[i * 4 + 1]);
                t16[i * 4 + 2] = fmaf(w2[(c + 2) * 9 + k], a.z, t16[i * 4 + 2]);
                t16[i * 4 + 3] = fmaf(w2[(c + 3) * 9 + k], a.w, t16[i * 4 + 3]);
            }
        }
    }
#pragma unroll
    for (int i = 0; i < 16; ++i) {
        int c = (cq << 4) + i;
        float inv = g2[c] * rsqrtf(v2[c] + 1e-5f);
        float sh  = b2[c] - m2[c] * inv;
        T2[w * 66 + c] = fmaxf(fmaf(t16[i], inv, sh), 0.f);
    }
    __syncthreads();

    float rT[64];
#pragma unroll
    for (int c4 = 0; c4 < 16; ++c4)
        *(float4*)&rT[c4 << 2] = *(const float4*)&T2[w * 66 + (c4 << 2)];

    const int hw = (h << 6) + w;
#pragma unroll 2
    for (int oo = 0; oo < 16; ++oo) {
        int o = (cq << 4) + oo;
        float inv = g3[o] * rsqrtf(v3[o] + 1e-5f);
        float sh  = b3[o] - m3[o] * inv;
        float acc = 0.f;
#pragma unroll
        for (int c = 0; c < 64; ++c) acc = fmaf(w3[o * 64 + c], rT[c], acc);
        size_t idx = (((size_t)((b << 6) + o)) << 12) + hw;
        out[idx] = fmaf(acc, inv, sh) + x[idx];
    }
}

// ---------------------------------------------------------------------------
extern "C" void kernel_launch(void* const* d_in, const int* in_sizes, int n_in,
                              void* d_out, int out_size, void* d_ws, size_t ws_size,
                              hipStream_t stream)
{
    const float* x  = (const float*)d_in[0];
    const float* w1 = (const float*)d_in[1];
    const float* g1 = (const float*)d_in[2];
    const float* b1 = (const float*)d_in[3];
    const float* m1 = (const float*)d_in[4];
    const float* v1 = (const float*)d_in[5];
    const float* w2 = (const float*)d_in[6];
    const float* g2 = (const float*)d_in[7];
    const float* b2 = (const float*)d_in[8];
    const float* m2 = (const float*)d_in[9];
    const float* v2 = (const float*)d_in[10];
    const float* w3 = (const float*)d_in[11];
    const float* g3 = (const float*)d_in[12];
    const float* b3 = (const float*)d_in[13];
    const float* m3 = (const float*)d_in[14];
    const float* v3 = (const float*)d_in[15];
    float* out = (float*)d_out;

    // ws: xT 4MB | vbf 4MB | O 4MB (bf16, normalized)
    unsigned short* xT  = (unsigned short*)d_ws;
    unsigned short* vbf = xT + (size_t)8 * 4096 * 64;
    unsigned short* Obase = (unsigned short*)((char*)d_ws + (8u << 20));

    k_prep<<<1024, 256, 0, stream>>>(x, w1, g1, b1, m1, v1, xT, vbf);
    k_attn<<<512, 512, 0, stream>>>(xT, vbf, Obase);
    k_post<<<512, 256, 0, stream>>>(Obase, x, w2, g2, b2, m2, v2,
                                    w3, g3, b3, m3, v3, out);
}